// Round 3
// baseline (295.594 us; speedup 1.0000x reference)
//
#include <hip/hip_runtime.h>
#include <cstdint>

#define AS1C(p) ((const __attribute__((address_space(1))) void*)(p))
#define AS3(p)  ((__attribute__((address_space(3))) void*)(p))

typedef __bf16 bf16x8 __attribute__((ext_vector_type(8)));
typedef __bf16 bf16x2 __attribute__((ext_vector_type(2)));
typedef float  f32x4  __attribute__((ext_vector_type(4)));

constexpr int B_ = 32, T_ = 512, D_ = 512, E_ = 8, H_ = 2048;
constexpr int S_ = 16;  // mean-pool split factor

// ---------------- fused x -> bf16 convert + partial mean-pool ----------------
__global__ __launch_bounds__(256)
void pool_cvt_kernel(const float* __restrict__ x, __bf16* __restrict__ xbf,
                     float* __restrict__ partial /*[B][S][D]*/) {
  const int b = blockIdx.x, s = blockIdx.y;
  const int tid = threadIdx.x;
  const size_t base = (size_t)b * T_ * D_ + (size_t)s * (T_ / S_) * D_;
  const float* xb = x + base;
  __bf16* ob = xbf + base;
  const int d0 = tid * 2;
  float s0 = 0.f, s1 = 0.f;
#pragma unroll
  for (int t = 0; t < T_ / S_; ++t) {
    float2 v = *reinterpret_cast<const float2*>(&xb[t * D_ + d0]);
    s0 += v.x; s1 += v.y;
    bf16x2 h; h[0] = (__bf16)v.x; h[1] = (__bf16)v.y;
    *reinterpret_cast<bf16x2*>(&ob[t * D_ + d0]) = h;
  }
  float* p = partial + ((size_t)b * S_ + s) * D_;
  p[d0] = s0; p[d0 + 1] = s1;
}

// ---------------- router finisher ----------------
__global__ void router2_kernel(const float* __restrict__ partial, const float* __restrict__ Wp,
                               const float* __restrict__ bp, float* __restrict__ probs_out,
                               float* __restrict__ chosen_out_f, int* __restrict__ chosen_ws) {
  const int b = blockIdx.x;
  const int tid = threadIdx.x;  // 512 threads, one per d
  __shared__ float pooled[D_];
  __shared__ float part[E_][64];
  __shared__ float logits[E_];
  const float* p = partial + (size_t)b * S_ * D_;
  float s = 0.f;
#pragma unroll
  for (int i = 0; i < S_; ++i) s += p[i * D_ + tid];
  pooled[tid] = s * (1.0f / (float)T_);
  __syncthreads();
  const int e = tid >> 6, dl = tid & 63;
  float acc = 0.f;
  for (int d = dl; d < D_; d += 64) acc += pooled[d] * Wp[d * E_ + e];
  part[e][dl] = acc;
  __syncthreads();
  if (tid < E_) {
    float sum = bp[tid];
#pragma unroll
    for (int i = 0; i < 64; ++i) sum += part[tid][i];
    logits[tid] = sum;
  }
  __syncthreads();
  if (tid == 0) {
    float mx = logits[0]; int arg = 0;
    for (int i = 1; i < E_; ++i) if (logits[i] > mx) { mx = logits[i]; arg = i; }
    float ex[E_], se = 0.f;
    for (int i = 0; i < E_; ++i) { ex[i] = expf(logits[i] - mx); se += ex[i]; }
    const float inv = 1.0f / se;
    for (int i = 0; i < E_; ++i) probs_out[b * E_ + i] = ex[i] * inv;
    chosen_out_f[b] = (float)arg;
    chosen_ws[b] = arg;
  }
}

// ---------------- merged transpose+convert for W1 and W2 ----------------
__global__ __launch_bounds__(256)
void transpose_cvt2_kernel(const float* __restrict__ W1, const float* __restrict__ W2,
                           __bf16* __restrict__ w1t, __bf16* __restrict__ w2t) {
  const int z = blockIdx.z;
  const float* src; __bf16* dst; int R, C;
  if (z < E_) { src = W1 + (size_t)z * D_ * H_; dst = w1t + (size_t)z * D_ * H_; R = D_; C = H_; }
  else        { src = W2 + (size_t)(z - E_) * H_ * D_; dst = w2t + (size_t)(z - E_) * H_ * D_; R = H_; C = D_; }
  const int nTc = C >> 6;
  const int c0 = (blockIdx.x % nTc) * 64;
  const int r0 = (blockIdx.x / nTc) * 64;
  __shared__ float t[64][65];
  const int tid = threadIdx.x;
  const int lx = tid & 15, ly = tid >> 4;
#pragma unroll
  for (int i = 0; i < 4; ++i) {
    const int r = ly + i * 16;
    float4 v = *reinterpret_cast<const float4*>(&src[(size_t)(r0 + r) * C + c0 + lx * 4]);
    t[r][lx * 4 + 0] = v.x; t[r][lx * 4 + 1] = v.y;
    t[r][lx * 4 + 2] = v.z; t[r][lx * 4 + 3] = v.w;
  }
  __syncthreads();
#pragma unroll
  for (int h = 0; h < 2; ++h) {
    const int chunk = tid + h * 256;
    const int cc = chunk >> 3;
    const int rr = (chunk & 7) * 8;
    bf16x8 o;
#pragma unroll
    for (int j = 0; j < 8; ++j) o[j] = (__bf16)t[rr + j][cc];
    *reinterpret_cast<bf16x8*>(&dst[(size_t)(c0 + cc) * R + r0 + rr]) = o;
  }
}

// ---------------- batched GEMM, B^T input, 128m x (NFR*32)n tile, BK=32 ----------------
// NFR = n-fragments per wave (4 -> BN=128, 2 -> BN=64). Waves 2x2 (wm=w>>1, wn=w&1).
// XOR-swizzled LDS (R2-verified): slot q of row r holds khalf q^((r>>1)&3).
template <int K, int N, int NFR, bool RELU, typename OutT>
__global__ __launch_bounds__(256, 4)
void gemm_bt_kernel(const __bf16* __restrict__ Aall, const __bf16* __restrict__ BTall,
                    const float* __restrict__ biasAll, OutT* __restrict__ Call,
                    const int* __restrict__ chosen) {
  constexpr int BN = NFR * 32;
  const int b = blockIdx.z;
  const int e = chosen[b];
  const __bf16* A  = Aall  + (size_t)b * 512 * K;
  const __bf16* BT = BTall + (size_t)e * N * K;
  const float* bias = biasAll + (size_t)e * N;
  OutT* C = Call + (size_t)b * 512 * N;
  const int m0 = blockIdx.y * 128;
  const int n0 = blockIdx.x * BN;

  __shared__ __bf16 As[128 * 32];
  __shared__ __bf16 Bs[BN * 32];

  const int tid  = threadIdx.x;
  const int lane = tid & 63;
  const int w    = tid >> 6;
  const int wm = w >> 1, wn = w & 1;
  const int l16  = lane & 15;
  const int quad = lane >> 4;
  const int qe   = (quad ^ ((l16 >> 1) & 3)) * 8;

  // per-lane staging geometry: each inst covers 16 rows; lane -> row r0l + (lane>>2),
  // source khalf swizzled by row.
  const int lrow = lane >> 2;
  const int lq   = lane & 3;

  f32x4 acc[4][NFR] = {};

  for (int k0 = 0; k0 < K; k0 += 32) {
#pragma unroll
    for (int j = 0; j < 2; ++j) {   // A: 8 insts total, 2 per wave
      const int r = (w * 2 + j) * 16 + lrow;
      const int qs = lq ^ ((r >> 1) & 3);
      __builtin_amdgcn_global_load_lds(AS1C(A + (size_t)(m0 + r) * K + k0 + qs * 8),
                                       AS3(As + (w * 2 + j) * 512), 16, 0, 0);
    }
#pragma unroll
    for (int j = 0; j < BN / 64; ++j) {  // B: BN/16 insts total, BN/64 per wave
      const int r = (w * (BN / 64) + j) * 16 + lrow;
      const int qs = lq ^ ((r >> 1) & 3);
      __builtin_amdgcn_global_load_lds(AS1C(BT + (size_t)(n0 + r) * K + k0 + qs * 8),
                                       AS3(Bs + (w * (BN / 64) + j) * 512), 16, 0, 0);
    }
    asm volatile("s_waitcnt vmcnt(0)" ::: "memory");
    __syncthreads();
    bf16x8 bfr[NFR];
#pragma unroll
    for (int jn = 0; jn < NFR; ++jn)
      bfr[jn] = *reinterpret_cast<const bf16x8*>(&Bs[(wn * (NFR * 16) + jn * 16 + l16) * 32 + qe]);
#pragma unroll
    for (int i = 0; i < 4; ++i) {
      bf16x8 af = *reinterpret_cast<const bf16x8*>(&As[(wm * 64 + i * 16 + l16) * 32 + qe]);
#pragma unroll
      for (int jn = 0; jn < NFR; ++jn)
        acc[i][jn] = __builtin_amdgcn_mfma_f32_16x16x32_bf16(af, bfr[jn], acc[i][jn], 0, 0, 0);
    }
    __syncthreads();
  }

  // epilogue: C/D layout col=lane&15, row=quad*4+reg
#pragma unroll
  for (int jn = 0; jn < NFR; ++jn) {
    const int gn = n0 + wn * (NFR * 16) + jn * 16 + l16;
    const float bv = bias[gn];
#pragma unroll
    for (int i = 0; i < 4; ++i) {
      const int gm = m0 + wm * 64 + i * 16 + quad * 4;
#pragma unroll
      for (int r = 0; r < 4; ++r) {
        float v = acc[i][jn][r] + bv;
        if (RELU) v = fmaxf(v, 0.f);
        C[(size_t)(gm + r) * N + gn] = (OutT)v;
      }
    }
  }
}

extern "C" void kernel_launch(void* const* d_in, const int* in_sizes, int n_in,
                              void* d_out, int out_size, void* d_ws, size_t ws_size,
                              hipStream_t stream) {
  const float* x  = (const float*)d_in[0];
  const float* Wp = (const float*)d_in[1];
  const float* bp = (const float*)d_in[2];
  const float* W1 = (const float*)d_in[3];
  const float* b1 = (const float*)d_in[4];
  const float* W2 = (const float*)d_in[5];
  const float* b2 = (const float*)d_in[6];
  float* out = (float*)d_out;

  char* ws = (char*)d_ws;
  int*    chosen = (int*)ws;
  __bf16* xbf  = (__bf16*)(ws + 256);                          // 16 MB
  __bf16* w1t  = (__bf16*)(ws + 256 + (size_t)16777216);       // 16 MB  [E,H,D]
  __bf16* w2t  = (__bf16*)(ws + 256 + (size_t)2 * 16777216);   // 16 MB  [E,D,H]
  __bf16* hbuf = (__bf16*)(ws + 256 + (size_t)3 * 16777216);   // 64 MB  [B,T,H]

  float* final_out  = out;                                // [B,T,D]
  float* probs_out  = out + (size_t)B_ * T_ * D_;         // [B,E]
  float* chosen_out = probs_out + B_ * E_;                // [B,1] as float
  float* partial = out;  // [B][S][D] = 1 MB, consumed by router2 before gemm2 overwrites

  pool_cvt_kernel<<<dim3(B_, S_), 256, 0, stream>>>(x, xbf, partial);
  router2_kernel<<<B_, 512, 0, stream>>>(partial, Wp, bp, probs_out, chosen_out, chosen);
  transpose_cvt2_kernel<<<dim3(256, 1, 2 * E_), 256, 0, stream>>>(W1, W2, w1t, w2t);

  // h = relu(x @ W1[e] + b1[e])  : M=512,K=512,N=2048, bf16 out, BN=128
  gemm_bt_kernel<512, 2048, 4, true, __bf16>
      <<<dim3(16, 4, 32), 256, 0, stream>>>(xbf, w1t, b1, hbuf, chosen);
  // out = h @ W2[e] + b2[e]      : M=512,K=2048,N=512, f32 out, BN=64 -> 1024 blocks
  gemm_bt_kernel<2048, 512, 2, false, float>
      <<<dim3(8, 4, 32), 256, 0, stream>>>(hbuf, w2t, b2, final_out, chosen);
}

// Round 4
// 270.008 us; speedup vs baseline: 1.0948x; 1.0948x over previous
//
#include <hip/hip_runtime.h>
#include <cstdint>

#define AS1C(p) ((const __attribute__((address_space(1))) void*)(p))
#define AS3(p)  ((__attribute__((address_space(3))) void*)(p))

typedef __bf16 bf16x8 __attribute__((ext_vector_type(8)));
typedef __bf16 bf16x2 __attribute__((ext_vector_type(2)));
typedef float  f32x4  __attribute__((ext_vector_type(4)));

constexpr int B_ = 32, T_ = 512, D_ = 512, E_ = 8, H_ = 2048;
constexpr int S_ = 16;  // mean-pool split factor

// ---------------- fused x -> bf16 convert + partial mean-pool ----------------
__global__ __launch_bounds__(256)
void pool_cvt_kernel(const float* __restrict__ x, __bf16* __restrict__ xbf,
                     float* __restrict__ partial /*[B][S][D]*/) {
  const int b = blockIdx.x, s = blockIdx.y;
  const int tid = threadIdx.x;
  const size_t base = (size_t)b * T_ * D_ + (size_t)s * (T_ / S_) * D_;
  const float* xb = x + base;
  __bf16* ob = xbf + base;
  const int d0 = tid * 2;
  float s0 = 0.f, s1 = 0.f;
#pragma unroll
  for (int t = 0; t < T_ / S_; ++t) {
    float2 v = *reinterpret_cast<const float2*>(&xb[t * D_ + d0]);
    s0 += v.x; s1 += v.y;
    bf16x2 h; h[0] = (__bf16)v.x; h[1] = (__bf16)v.y;
    *reinterpret_cast<bf16x2*>(&ob[t * D_ + d0]) = h;
  }
  float* p = partial + ((size_t)b * S_ + s) * D_;
  p[d0] = s0; p[d0 + 1] = s1;
}

// ---------------- router finisher ----------------
__global__ void router2_kernel(const float* __restrict__ partial, const float* __restrict__ Wp,
                               const float* __restrict__ bp, float* __restrict__ probs_out,
                               float* __restrict__ chosen_out_f, int* __restrict__ chosen_ws) {
  const int b = blockIdx.x;
  const int tid = threadIdx.x;  // 512 threads, one per d
  __shared__ float pooled[D_];
  __shared__ float part[E_][64];
  __shared__ float logits[E_];
  const float* p = partial + (size_t)b * S_ * D_;
  float s = 0.f;
#pragma unroll
  for (int i = 0; i < S_; ++i) s += p[i * D_ + tid];
  pooled[tid] = s * (1.0f / (float)T_);
  __syncthreads();
  const int e = tid >> 6, dl = tid & 63;
  float acc = 0.f;
  for (int d = dl; d < D_; d += 64) acc += pooled[d] * Wp[d * E_ + e];
  part[e][dl] = acc;
  __syncthreads();
  if (tid < E_) {
    float sum = bp[tid];
#pragma unroll
    for (int i = 0; i < 64; ++i) sum += part[tid][i];
    logits[tid] = sum;
  }
  __syncthreads();
  if (tid == 0) {
    float mx = logits[0]; int arg = 0;
    for (int i = 1; i < E_; ++i) if (logits[i] > mx) { mx = logits[i]; arg = i; }
    float ex[E_], se = 0.f;
    for (int i = 0; i < E_; ++i) { ex[i] = expf(logits[i] - mx); se += ex[i]; }
    const float inv = 1.0f / se;
    for (int i = 0; i < E_; ++i) probs_out[b * E_ + i] = ex[i] * inv;
    chosen_out_f[b] = (float)arg;
    chosen_ws[b] = arg;
  }
}

// ---------------- merged transpose+convert for W1 and W2 ----------------
__global__ __launch_bounds__(256)
void transpose_cvt2_kernel(const float* __restrict__ W1, const float* __restrict__ W2,
                           __bf16* __restrict__ w1t, __bf16* __restrict__ w2t) {
  const int z = blockIdx.z;
  const float* src; __bf16* dst; int R, C;
  if (z < E_) { src = W1 + (size_t)z * D_ * H_; dst = w1t + (size_t)z * D_ * H_; R = D_; C = H_; }
  else        { src = W2 + (size_t)(z - E_) * H_ * D_; dst = w2t + (size_t)(z - E_) * H_ * D_; R = H_; C = D_; }
  const int nTc = C >> 6;
  const int c0 = (blockIdx.x % nTc) * 64;
  const int r0 = (blockIdx.x / nTc) * 64;
  __shared__ float t[64][65];
  const int tid = threadIdx.x;
  const int lx = tid & 15, ly = tid >> 4;
#pragma unroll
  for (int i = 0; i < 4; ++i) {
    const int r = ly + i * 16;
    float4 v = *reinterpret_cast<const float4*>(&src[(size_t)(r0 + r) * C + c0 + lx * 4]);
    t[r][lx * 4 + 0] = v.x; t[r][lx * 4 + 1] = v.y;
    t[r][lx * 4 + 2] = v.z; t[r][lx * 4 + 3] = v.w;
  }
  __syncthreads();
#pragma unroll
  for (int h = 0; h < 2; ++h) {
    const int chunk = tid + h * 256;
    const int cc = chunk >> 3;
    const int rr = (chunk & 7) * 8;
    bf16x8 o;
#pragma unroll
    for (int j = 0; j < 8; ++j) o[j] = (__bf16)t[rr + j][cc];
    *reinterpret_cast<bf16x8*>(&dst[(size_t)(c0 + cc) * R + r0 + rr]) = o;
  }
}

// ---------------- batched GEMM, B^T input, 128x128/BK32, XCD-swizzled 1D grid ----------------
// C[b] = epilogue(A[b] @ BT[e]^T + bias[e]); A:[512,K] k-contig, BT:[N,K] k-contig.
// Grid is 1D, size 32*4*NB (NB = N/128 n-blocks). Decode puts the NB n-blocks of a
// (b,m) group on ONE XCD (flat&7), dispatched back-to-back, so the group's A-tile is
// fetched from HBM once and served from that XCD's L2 thereafter.
// LDS bank swizzle (R2-verified, 0 conflicts): slot q of row r holds khalf q^((r>>1)&3).
template <int K, int N, int NB, bool RELU, typename OutT>
__global__ __launch_bounds__(256)
void gemm_bt_kernel(const __bf16* __restrict__ Aall, const __bf16* __restrict__ BTall,
                    const float* __restrict__ biasAll, OutT* __restrict__ Call,
                    const int* __restrict__ chosen) {
  const int flat = blockIdx.x;
  const int xcd = flat & 7;
  const int s = flat >> 3;
  const int n = s % NB;
  const int g = (s / NB) * 8 + xcd;   // group = b*4 + m, co-located per XCD
  const int m0 = (g & 3) * 128;
  const int b = g >> 2;

  const int e = chosen[b];
  const __bf16* A  = Aall  + (size_t)b * 512 * K;
  const __bf16* BT = BTall + (size_t)e * N * K;
  const float* bias = biasAll + (size_t)e * N;
  OutT* C = Call + (size_t)b * 512 * N;
  const int n0 = n * 128;

  __shared__ __bf16 As[128 * 32];
  __shared__ __bf16 Bs[128 * 32];

  const int tid  = threadIdx.x;
  const int lane = tid & 63;
  const int w    = tid >> 6;
  const int wm = w >> 1, wn = w & 1;
  const int l16  = lane & 15;
  const int quad = lane >> 4;
  const int qe   = (quad ^ ((l16 >> 1) & 3)) * 8;

  const int lrow = lane >> 2;   // staging: each inst covers 16 rows
  const int lq   = lane & 3;

  f32x4 acc[4][4] = {};

  for (int k0 = 0; k0 < K; k0 += 32) {
#pragma unroll
    for (int j = 0; j < 2; ++j) {
      const int r = (w * 2 + j) * 16 + lrow;
      const int qs = lq ^ ((r >> 1) & 3);
      __builtin_amdgcn_global_load_lds(AS1C(A + (size_t)(m0 + r) * K + k0 + qs * 8),
                                       AS3(As + (w * 2 + j) * 512), 16, 0, 0);
      __builtin_amdgcn_global_load_lds(AS1C(BT + (size_t)(n0 + r) * K + k0 + qs * 8),
                                       AS3(Bs + (w * 2 + j) * 512), 16, 0, 0);
    }
    asm volatile("s_waitcnt vmcnt(0)" ::: "memory");
    __syncthreads();
    bf16x8 bfr[4];
#pragma unroll
    for (int jn = 0; jn < 4; ++jn)
      bfr[jn] = *reinterpret_cast<const bf16x8*>(&Bs[(wn * 64 + jn * 16 + l16) * 32 + qe]);
#pragma unroll
    for (int i = 0; i < 4; ++i) {
      bf16x8 af = *reinterpret_cast<const bf16x8*>(&As[(wm * 64 + i * 16 + l16) * 32 + qe]);
#pragma unroll
      for (int jn = 0; jn < 4; ++jn)
        acc[i][jn] = __builtin_amdgcn_mfma_f32_16x16x32_bf16(af, bfr[jn], acc[i][jn], 0, 0, 0);
    }
    __syncthreads();
  }

  // epilogue: C/D layout col=lane&15, row=quad*4+reg
#pragma unroll
  for (int jn = 0; jn < 4; ++jn) {
    const int gn = n0 + wn * 64 + jn * 16 + l16;
    const float bv = bias[gn];
#pragma unroll
    for (int i = 0; i < 4; ++i) {
      const int gm = m0 + wm * 64 + i * 16 + quad * 4;
#pragma unroll
      for (int r = 0; r < 4; ++r) {
        float v = acc[i][jn][r] + bv;
        if (RELU) v = fmaxf(v, 0.f);
        C[(size_t)(gm + r) * N + gn] = (OutT)v;
      }
    }
  }
}

extern "C" void kernel_launch(void* const* d_in, const int* in_sizes, int n_in,
                              void* d_out, int out_size, void* d_ws, size_t ws_size,
                              hipStream_t stream) {
  const float* x  = (const float*)d_in[0];
  const float* Wp = (const float*)d_in[1];
  const float* bp = (const float*)d_in[2];
  const float* W1 = (const float*)d_in[3];
  const float* b1 = (const float*)d_in[4];
  const float* W2 = (const float*)d_in[5];
  const float* b2 = (const float*)d_in[6];
  float* out = (float*)d_out;

  char* ws = (char*)d_ws;
  int*    chosen = (int*)ws;
  __bf16* xbf  = (__bf16*)(ws + 256);                          // 16 MB
  __bf16* w1t  = (__bf16*)(ws + 256 + (size_t)16777216);       // 16 MB  [E,H,D]
  __bf16* w2t  = (__bf16*)(ws + 256 + (size_t)2 * 16777216);   // 16 MB  [E,D,H]
  __bf16* hbuf = (__bf16*)(ws + 256 + (size_t)3 * 16777216);   // 64 MB  [B,T,H]

  float* final_out  = out;                                // [B,T,D]
  float* probs_out  = out + (size_t)B_ * T_ * D_;         // [B,E]
  float* chosen_out = probs_out + B_ * E_;                // [B,1] as float
  float* partial = out;  // [B][S][D] = 1 MB, consumed by router2 before gemm2 overwrites

  pool_cvt_kernel<<<dim3(B_, S_), 256, 0, stream>>>(x, xbf, partial);
  router2_kernel<<<B_, 512, 0, stream>>>(partial, Wp, bp, probs_out, chosen_out, chosen);
  transpose_cvt2_kernel<<<dim3(256, 1, 2 * E_), 256, 0, stream>>>(W1, W2, w1t, w2t);

  // h = relu(x @ W1[e] + b1[e])  : M=512,K=512,N=2048, bf16 out; 32*4*16 = 2048 blocks
  gemm_bt_kernel<512, 2048, 16, true, __bf16>
      <<<dim3(2048), 256, 0, stream>>>(xbf, w1t, b1, hbuf, chosen);
  // out = h @ W2[e] + b2[e]      : M=512,K=2048,N=512, f32 out; 32*4*4 = 512 blocks
  gemm_bt_kernel<2048, 512, 4, false, float>
      <<<dim3(512), 256, 0, stream>>>(hbuf, w2t, b2, final_out, chosen);
}

// Round 5
// 268.885 us; speedup vs baseline: 1.0993x; 1.0042x over previous
//
#include <hip/hip_runtime.h>
#include <cstdint>

#define AS1C(p) ((const __attribute__((address_space(1))) void*)(p))
#define AS3(p)  ((__attribute__((address_space(3))) void*)(p))

typedef __bf16 bf16x8 __attribute__((ext_vector_type(8)));
typedef __bf16 bf16x4 __attribute__((ext_vector_type(4)));
typedef float  f32x4  __attribute__((ext_vector_type(4)));

constexpr int B_ = 32, T_ = 512, D_ = 512, E_ = 8, H_ = 2048;
constexpr int S_ = 16;   // pool blocks per utterance
constexpr int P_ = 32;   // partial slots per utterance (2 per pool block)

// ---------------- fused prep: x->bf16 + partial mean-pool, and W1/W2 transpose+cvt ----------------
// blocks [0,512): pool.  blocks [512, 4608): 64x64 transpose tiles (16 slabs x 256 tiles).
__global__ __launch_bounds__(256)
void prep_kernel(const float* __restrict__ x, __bf16* __restrict__ xbf,
                 float* __restrict__ partial /*[B][P_][D]*/,
                 const float* __restrict__ W1, const float* __restrict__ W2,
                 __bf16* __restrict__ w1t, __bf16* __restrict__ w2t) {
  __shared__ float t[64][65];
  const int blk = blockIdx.x;
  const int tid = threadIdx.x;
  if (blk < B_ * S_) {
    // ---- pool + convert: rows [s*32, s*32+32) of utterance b ----
    const int b = blk >> 4, s = blk & 15;
    const int c = (tid & 127) * 4;      // column (float4)
    const int half = tid >> 7;          // row parity
    const size_t base = (size_t)b * T_ * D_ + (size_t)(s * 32) * D_;
    const float* xb = x + base;
    __bf16* ob = xbf + base;
    f32x4 acc = {0.f, 0.f, 0.f, 0.f};
#pragma unroll
    for (int i = 0; i < 16; ++i) {
      const int tr = half + 2 * i;
      f32x4 v = *reinterpret_cast<const f32x4*>(&xb[(size_t)tr * D_ + c]);
      acc += v;
      bf16x4 h; h[0] = (__bf16)v[0]; h[1] = (__bf16)v[1]; h[2] = (__bf16)v[2]; h[3] = (__bf16)v[3];
      *reinterpret_cast<bf16x4*>(&ob[(size_t)tr * D_ + c]) = h;
    }
    float* p = partial + ((size_t)b * P_ + (s * 2 + half)) * D_ + c;
    *reinterpret_cast<f32x4*>(p) = acc;
  } else {
    // ---- transpose+convert one 64x64 tile ----
    const int idx = blk - B_ * S_;
    const int z = idx >> 8;             // slab: 0..7 W1, 8..15 W2
    const int tt = idx & 255;
    const float* src; __bf16* dst; int R, C;
    if (z < E_) { src = W1 + (size_t)z * D_ * H_; dst = w1t + (size_t)z * D_ * H_; R = D_; C = H_; }
    else        { src = W2 + (size_t)(z - E_) * H_ * D_; dst = w2t + (size_t)(z - E_) * H_ * D_; R = H_; C = D_; }
    const int nTc = C >> 6;
    const int c0 = (tt % nTc) * 64;
    const int r0 = (tt / nTc) * 64;
    const int lx = tid & 15, ly = tid >> 4;
#pragma unroll
    for (int i = 0; i < 4; ++i) {
      const int r = ly + i * 16;
      float4 v = *reinterpret_cast<const float4*>(&src[(size_t)(r0 + r) * C + c0 + lx * 4]);
      t[r][lx * 4 + 0] = v.x; t[r][lx * 4 + 1] = v.y;
      t[r][lx * 4 + 2] = v.z; t[r][lx * 4 + 3] = v.w;
    }
    __syncthreads();
#pragma unroll
    for (int h = 0; h < 2; ++h) {
      const int chunk = tid + h * 256;
      const int cc = chunk >> 3;
      const int rr = (chunk & 7) * 8;
      bf16x8 o;
#pragma unroll
      for (int j = 0; j < 8; ++j) o[j] = (__bf16)t[rr + j][cc];
      *reinterpret_cast<bf16x8*>(&dst[(size_t)(c0 + cc) * R + r0 + rr]) = o;
    }
  }
}

// ---------------- router finisher ----------------
__global__ void router2_kernel(const float* __restrict__ partial, const float* __restrict__ Wp,
                               const float* __restrict__ bp, float* __restrict__ probs_out,
                               float* __restrict__ chosen_out_f, int* __restrict__ chosen_ws) {
  const int b = blockIdx.x;
  const int tid = threadIdx.x;  // 512 threads, one per d
  __shared__ float pooled[D_];
  __shared__ float part[E_][64];
  __shared__ float logits[E_];
  const float* p = partial + (size_t)b * P_ * D_;
  float s = 0.f;
#pragma unroll
  for (int i = 0; i < P_; ++i) s += p[i * D_ + tid];
  pooled[tid] = s * (1.0f / (float)T_);
  __syncthreads();
  const int e = tid >> 6, dl = tid & 63;
  float acc = 0.f;
  for (int d = dl; d < D_; d += 64) acc += pooled[d] * Wp[d * E_ + e];
  part[e][dl] = acc;
  __syncthreads();
  if (tid < E_) {
    float sum = bp[tid];
#pragma unroll
    for (int i = 0; i < 64; ++i) sum += part[tid][i];
    logits[tid] = sum;
  }
  __syncthreads();
  if (tid == 0) {
    float mx = logits[0]; int arg = 0;
    for (int i = 1; i < E_; ++i) if (logits[i] > mx) { mx = logits[i]; arg = i; }
    float ex[E_], se = 0.f;
    for (int i = 0; i < E_; ++i) { ex[i] = expf(logits[i] - mx); se += ex[i]; }
    const float inv = 1.0f / se;
    for (int i = 0; i < E_; ++i) probs_out[b * E_ + i] = ex[i] * inv;
    chosen_out_f[b] = (float)arg;
    chosen_ws[b] = arg;
  }
}

// ---------------- batched GEMM, B^T input, 128x128/BK32, double-buffered LDS ----------------
// C[b] = epilogue(A[b] @ BT[e]^T + bias[e]); A:[512,K] k-contig, BT:[N,K] k-contig.
// Per iter: drain+barrier, issue next tile's global_load_lds into other buffer, compute current
// -> loads overlap the previous iteration's 16 MFMAs instead of stalling at issue.
// LDS bank swizzle (R2-verified, 0 conflicts): slot q of row r holds khalf q^((r>>1)&3).
template <int K, int N, bool RELU, typename OutT>
__global__ __launch_bounds__(256)
void gemm_bt_kernel(const __bf16* __restrict__ Aall, const __bf16* __restrict__ BTall,
                    const float* __restrict__ biasAll, OutT* __restrict__ Call,
                    const int* __restrict__ chosen) {
  const int b = blockIdx.z;
  const int e = chosen[b];
  const __bf16* A  = Aall  + (size_t)b * 512 * K;
  const __bf16* BT = BTall + (size_t)e * N * K;
  const float* bias = biasAll + (size_t)e * N;
  OutT* C = Call + (size_t)b * 512 * N;
  const int m0 = blockIdx.y * 128;
  const int n0 = blockIdx.x * 128;

  __shared__ __bf16 As[2][128 * 32];
  __shared__ __bf16 Bs[2][128 * 32];

  const int tid  = threadIdx.x;
  const int lane = tid & 63;
  const int w    = tid >> 6;
  const int wm = w >> 1, wn = w & 1;
  const int l16  = lane & 15;
  const int quad = lane >> 4;
  const int qe   = (quad ^ ((l16 >> 1) & 3)) * 8;
  const int lrow = lane >> 2;
  const int lq   = lane & 3;

  f32x4 acc[4][4] = {};

  auto stage = [&](int buf, int k0) {
#pragma unroll
    for (int j = 0; j < 2; ++j) {
      const int r = (w * 2 + j) * 16 + lrow;
      const int qs = lq ^ ((r >> 1) & 3);
      __builtin_amdgcn_global_load_lds(AS1C(A + (size_t)(m0 + r) * K + k0 + qs * 8),
                                       AS3(&As[buf][(w * 2 + j) * 512]), 16, 0, 0);
      __builtin_amdgcn_global_load_lds(AS1C(BT + (size_t)(n0 + r) * K + k0 + qs * 8),
                                       AS3(&Bs[buf][(w * 2 + j) * 512]), 16, 0, 0);
    }
  };
  auto compute = [&](int buf) {
    bf16x8 af[4], bfr[4];
#pragma unroll
    for (int i = 0; i < 4; ++i) {
      af[i]  = *reinterpret_cast<const bf16x8*>(&As[buf][(wm * 64 + i * 16 + l16) * 32 + qe]);
      bfr[i] = *reinterpret_cast<const bf16x8*>(&Bs[buf][(wn * 64 + i * 16 + l16) * 32 + qe]);
    }
#pragma unroll
    for (int i = 0; i < 4; ++i)
#pragma unroll
      for (int jn = 0; jn < 4; ++jn)
        acc[i][jn] = __builtin_amdgcn_mfma_f32_16x16x32_bf16(af[i], bfr[jn], acc[i][jn], 0, 0, 0);
  };

  constexpr int NIT = K / 32;  // even for both instantiations
  stage(0, 0);
  for (int it = 0; it < NIT; it += 2) {
    asm volatile("s_waitcnt vmcnt(0)" ::: "memory");
    __syncthreads();
    stage(1, (it + 1) * 32);          // it+1 < NIT always (NIT even)
    compute(0);
    asm volatile("s_waitcnt vmcnt(0)" ::: "memory");
    __syncthreads();
    if (it + 2 < NIT) stage(0, (it + 2) * 32);
    compute(1);
  }

  // epilogue: C/D layout col=lane&15, row=quad*4+reg
#pragma unroll
  for (int jn = 0; jn < 4; ++jn) {
    const int gn = n0 + wn * 64 + jn * 16 + l16;
    const float bv = bias[gn];
#pragma unroll
    for (int i = 0; i < 4; ++i) {
      const int gm = m0 + wm * 64 + i * 16 + quad * 4;
#pragma unroll
      for (int r = 0; r < 4; ++r) {
        float v = acc[i][jn][r] + bv;
        if (RELU) v = fmaxf(v, 0.f);
        C[(size_t)(gm + r) * N + gn] = (OutT)v;
      }
    }
  }
}

extern "C" void kernel_launch(void* const* d_in, const int* in_sizes, int n_in,
                              void* d_out, int out_size, void* d_ws, size_t ws_size,
                              hipStream_t stream) {
  const float* x  = (const float*)d_in[0];
  const float* Wp = (const float*)d_in[1];
  const float* bp = (const float*)d_in[2];
  const float* W1 = (const float*)d_in[3];
  const float* b1 = (const float*)d_in[4];
  const float* W2 = (const float*)d_in[5];
  const float* b2 = (const float*)d_in[6];
  float* out = (float*)d_out;

  char* ws = (char*)d_ws;
  int*    chosen = (int*)ws;
  __bf16* xbf  = (__bf16*)(ws + 256);                          // 16 MB
  __bf16* w1t  = (__bf16*)(ws + 256 + (size_t)16777216);       // 16 MB  [E,H,D]
  __bf16* w2t  = (__bf16*)(ws + 256 + (size_t)2 * 16777216);   // 16 MB  [E,D,H]
  __bf16* hbuf = (__bf16*)(ws + 256 + (size_t)3 * 16777216);   // 64 MB  [B,T,H]

  float* final_out  = out;                                // [B,T,D]
  float* probs_out  = out + (size_t)B_ * T_ * D_;         // [B,E]
  float* chosen_out = probs_out + B_ * E_;                // [B,1] as float
  float* partial = out;  // [B][P_][D] = 2 MB, consumed by router2 before gemm2 overwrites

  prep_kernel<<<dim3(B_ * S_ + 16 * 256), 256, 0, stream>>>(x, xbf, partial, W1, W2, w1t, w2t);
  router2_kernel<<<B_, 512, 0, stream>>>(partial, Wp, bp, probs_out, chosen_out, chosen);

  // h = relu(x @ W1[e] + b1[e])  : M=512,K=512,N=2048, bf16 out
  gemm_bt_kernel<512, 2048, true, __bf16>
      <<<dim3(16, 4, 32), 256, 0, stream>>>(xbf, w1t, b1, hbuf, chosen);
  // out = h @ W2[e] + b2[e]      : M=512,K=2048,N=512, f32 out
  gemm_bt_kernel<2048, 512, false, float>
      <<<dim3(4, 4, 32), 256, 0, stream>>>(hbuf, w2t, b2, final_out, chosen);
}

// Round 6
// 250.710 us; speedup vs baseline: 1.1790x; 1.0725x over previous
//
#include <hip/hip_runtime.h>
#include <cstdint>

#define AS1C(p) ((const __attribute__((address_space(1))) void*)(p))
#define AS3(p)  ((__attribute__((address_space(3))) void*)(p))

typedef __bf16 bf16x8 __attribute__((ext_vector_type(8)));
typedef __bf16 bf16x4 __attribute__((ext_vector_type(4)));
typedef float  f32x4  __attribute__((ext_vector_type(4)));

constexpr int B_ = 32, T_ = 512, D_ = 512, E_ = 8, H_ = 2048;
constexpr int S_ = 16;   // pool blocks per utterance
constexpr int P_ = 32;   // partial slots per utterance (2 per pool block)

// ---------------- fused prep: x->bf16 + partial mean-pool, and W1/W2 transpose+cvt ----------------
// blocks [0,512): pool.  blocks [512, 4608): 64x64 transpose tiles (16 slabs x 256 tiles).
__global__ __launch_bounds__(256)
void prep_kernel(const float* __restrict__ x, __bf16* __restrict__ xbf,
                 float* __restrict__ partial /*[B][P_][D]*/,
                 const float* __restrict__ W1, const float* __restrict__ W2,
                 __bf16* __restrict__ w1t, __bf16* __restrict__ w2t) {
  __shared__ float t[64][65];
  const int blk = blockIdx.x;
  const int tid = threadIdx.x;
  if (blk < B_ * S_) {
    // ---- pool + convert: rows [s*32, s*32+32) of utterance b ----
    const int b = blk >> 4, s = blk & 15;
    const int c = (tid & 127) * 4;      // column (float4)
    const int half = tid >> 7;          // row parity
    const size_t base = (size_t)b * T_ * D_ + (size_t)(s * 32) * D_;
    const float* xb = x + base;
    __bf16* ob = xbf + base;
    f32x4 acc = {0.f, 0.f, 0.f, 0.f};
#pragma unroll
    for (int i = 0; i < 16; ++i) {
      const int tr = half + 2 * i;
      f32x4 v = *reinterpret_cast<const f32x4*>(&xb[(size_t)tr * D_ + c]);
      acc += v;
      bf16x4 h; h[0] = (__bf16)v[0]; h[1] = (__bf16)v[1]; h[2] = (__bf16)v[2]; h[3] = (__bf16)v[3];
      *reinterpret_cast<bf16x4*>(&ob[(size_t)tr * D_ + c]) = h;
    }
    float* p = partial + ((size_t)b * P_ + (s * 2 + half)) * D_ + c;
    *reinterpret_cast<f32x4*>(p) = acc;
  } else {
    // ---- transpose+convert one 64x64 tile ----
    const int idx = blk - B_ * S_;
    const int z = idx >> 8;             // slab: 0..7 W1, 8..15 W2
    const int tt = idx & 255;
    const float* src; __bf16* dst; int R, C;
    if (z < E_) { src = W1 + (size_t)z * D_ * H_; dst = w1t + (size_t)z * D_ * H_; R = D_; C = H_; }
    else        { src = W2 + (size_t)(z - E_) * H_ * D_; dst = w2t + (size_t)(z - E_) * H_ * D_; R = H_; C = D_; }
    const int nTc = C >> 6;
    const int c0 = (tt % nTc) * 64;
    const int r0 = (tt / nTc) * 64;
    const int lx = tid & 15, ly = tid >> 4;
#pragma unroll
    for (int i = 0; i < 4; ++i) {
      const int r = ly + i * 16;
      float4 v = *reinterpret_cast<const float4*>(&src[(size_t)(r0 + r) * C + c0 + lx * 4]);
      t[r][lx * 4 + 0] = v.x; t[r][lx * 4 + 1] = v.y;
      t[r][lx * 4 + 2] = v.z; t[r][lx * 4 + 3] = v.w;
    }
    __syncthreads();
#pragma unroll
    for (int h = 0; h < 2; ++h) {
      const int chunk = tid + h * 256;
      const int cc = chunk >> 3;
      const int rr = (chunk & 7) * 8;
      bf16x8 o;
#pragma unroll
      for (int j = 0; j < 8; ++j) o[j] = (__bf16)t[rr + j][cc];
      *reinterpret_cast<bf16x8*>(&dst[(size_t)(c0 + cc) * R + r0 + rr]) = o;
    }
  }
}

// ---------------- router finisher ----------------
__global__ void router2_kernel(const float* __restrict__ partial, const float* __restrict__ Wp,
                               const float* __restrict__ bp, float* __restrict__ probs_out,
                               float* __restrict__ chosen_out_f, int* __restrict__ chosen_ws) {
  const int b = blockIdx.x;
  const int tid = threadIdx.x;  // 512 threads, one per d
  __shared__ float pooled[D_];
  __shared__ float part[E_][64];
  __shared__ float logits[E_];
  const float* p = partial + (size_t)b * P_ * D_;
  float s = 0.f;
#pragma unroll
  for (int i = 0; i < P_; ++i) s += p[i * D_ + tid];
  pooled[tid] = s * (1.0f / (float)T_);
  __syncthreads();
  const int e = tid >> 6, dl = tid & 63;
  float acc = 0.f;
  for (int d = dl; d < D_; d += 64) acc += pooled[d] * Wp[d * E_ + e];
  part[e][dl] = acc;
  __syncthreads();
  if (tid < E_) {
    float sum = bp[tid];
#pragma unroll
    for (int i = 0; i < 64; ++i) sum += part[tid][i];
    logits[tid] = sum;
  }
  __syncthreads();
  if (tid == 0) {
    float mx = logits[0]; int arg = 0;
    for (int i = 1; i < E_; ++i) if (logits[i] > mx) { mx = logits[i]; arg = i; }
    float ex[E_], se = 0.f;
    for (int i = 0; i < E_; ++i) { ex[i] = expf(logits[i] - mx); se += ex[i]; }
    const float inv = 1.0f / se;
    for (int i = 0; i < E_; ++i) probs_out[b * E_ + i] = ex[i] * inv;
    chosen_out_f[b] = (float)arg;
    chosen_ws[b] = arg;
  }
}

// ---------------- batched GEMM, B^T input, 128x128 tile, BK=64, single-buffered ----------------
// C[b] = epilogue(A[b] @ BT[e]^T + bias[e]); A:[512,K] k-contig, BT:[N,K] k-contig.
// One vmcnt(0)+barrier pair per 32 MFMAs (BK=64) instead of per 16 (BK=32) -- amortizes the
// structural barrier drain. LDS row = 64 bf16 = 8 slots of 16B; slot p of row r holds
// logical k-slot p^(r&7): staging src-k becomes a pure lane function, fragment reads land
// 2 lanes/bank (free, m136). R2 verified 0 conflicts for the 4-slot variant of this scheme.
template <int K, int N, bool RELU, typename OutT>
__global__ __launch_bounds__(256)
void gemm_bt_kernel(const __bf16* __restrict__ Aall, const __bf16* __restrict__ BTall,
                    const float* __restrict__ biasAll, OutT* __restrict__ Call,
                    const int* __restrict__ chosen) {
  const int b = blockIdx.z;
  const int e = chosen[b];
  const __bf16* A  = Aall  + (size_t)b * 512 * K;
  const __bf16* BT = BTall + (size_t)e * N * K;
  const float* bias = biasAll + (size_t)e * N;
  OutT* C = Call + (size_t)b * 512 * N;
  const int m0 = blockIdx.y * 128;
  const int n0 = blockIdx.x * 128;

  __shared__ __bf16 As[128 * 64];  // 16 KB
  __shared__ __bf16 Bs[128 * 64];  // 16 KB

  const int tid  = threadIdx.x;
  const int lane = tid & 63;
  const int w    = tid >> 6;
  const int wm = w >> 1, wn = w & 1;
  const int l16  = lane & 15;
  const int quad = lane >> 4;
  const int lr8  = lane >> 3;                       // staging row-within-8
  const int qsrc = ((lane & 7) ^ (lr8 & 7)) * 8;    // swizzled source k-offset (lane-pure)
  const int swl  = (l16 & 7);                       // read-side row swizzle key

  f32x4 acc[4][4] = {};

  for (int k0 = 0; k0 < K; k0 += 64) {
#pragma unroll
    for (int j = 0; j < 4; ++j) {                   // 4 insts A + 4 insts B per wave
      const int r = (w * 4 + j) * 8 + lr8;
      __builtin_amdgcn_global_load_lds(AS1C(A + (size_t)(m0 + r) * K + k0 + qsrc),
                                       AS3(As + (w * 4 + j) * 512), 16, 0, 0);
      __builtin_amdgcn_global_load_lds(AS1C(BT + (size_t)(n0 + r) * K + k0 + qsrc),
                                       AS3(Bs + (w * 4 + j) * 512), 16, 0, 0);
    }
    asm volatile("s_waitcnt vmcnt(0)" ::: "memory");
    __syncthreads();
#pragma unroll
    for (int h = 0; h < 2; ++h) {                   // two k-halves of 32
      const int ls = ((h * 4 + quad) ^ swl) * 8;    // physical slot offset (bf16 elems)
      bf16x8 af[4], bfr[4];
#pragma unroll
      for (int i = 0; i < 4; ++i) {
        af[i]  = *reinterpret_cast<const bf16x8*>(&As[(wm * 64 + i * 16 + l16) * 64 + ls]);
        bfr[i] = *reinterpret_cast<const bf16x8*>(&Bs[(wn * 64 + i * 16 + l16) * 64 + ls]);
      }
#pragma unroll
      for (int i = 0; i < 4; ++i)
#pragma unroll
        for (int jn = 0; jn < 4; ++jn)
          acc[i][jn] = __builtin_amdgcn_mfma_f32_16x16x32_bf16(af[i], bfr[jn], acc[i][jn], 0, 0, 0);
    }
    __syncthreads();
  }

  // epilogue: C/D layout col=lane&15, row=quad*4+reg
#pragma unroll
  for (int jn = 0; jn < 4; ++jn) {
    const int gn = n0 + wn * 64 + jn * 16 + l16;
    const float bv = bias[gn];
#pragma unroll
    for (int i = 0; i < 4; ++i) {
      const int gm = m0 + wm * 64 + i * 16 + quad * 4;
#pragma unroll
      for (int r = 0; r < 4; ++r) {
        float v = acc[i][jn][r] + bv;
        if (RELU) v = fmaxf(v, 0.f);
        C[(size_t)(gm + r) * N + gn] = (OutT)v;
      }
    }
  }
}

extern "C" void kernel_launch(void* const* d_in, const int* in_sizes, int n_in,
                              void* d_out, int out_size, void* d_ws, size_t ws_size,
                              hipStream_t stream) {
  const float* x  = (const float*)d_in[0];
  const float* Wp = (const float*)d_in[1];
  const float* bp = (const float*)d_in[2];
  const float* W1 = (const float*)d_in[3];
  const float* b1 = (const float*)d_in[4];
  const float* W2 = (const float*)d_in[5];
  const float* b2 = (const float*)d_in[6];
  float* out = (float*)d_out;

  char* ws = (char*)d_ws;
  int*    chosen = (int*)ws;
  __bf16* xbf  = (__bf16*)(ws + 256);                          // 16 MB
  __bf16* w1t  = (__bf16*)(ws + 256 + (size_t)16777216);       // 16 MB  [E,H,D]
  __bf16* w2t  = (__bf16*)(ws + 256 + (size_t)2 * 16777216);   // 16 MB  [E,D,H]
  __bf16* hbuf = (__bf16*)(ws + 256 + (size_t)3 * 16777216);   // 64 MB  [B,T,H]

  float* final_out  = out;                                // [B,T,D]
  float* probs_out  = out + (size_t)B_ * T_ * D_;         // [B,E]
  float* chosen_out = probs_out + B_ * E_;                // [B,1] as float
  float* partial = out;  // [B][P_][D] = 2 MB, consumed by router2 before gemm2 overwrites

  prep_kernel<<<dim3(B_ * S_ + 16 * 256), 256, 0, stream>>>(x, xbf, partial, W1, W2, w1t, w2t);
  router2_kernel<<<B_, 512, 0, stream>>>(partial, Wp, bp, probs_out, chosen_out, chosen);

  // h = relu(x @ W1[e] + b1[e])  : M=512,K=512,N=2048, bf16 out
  gemm_bt_kernel<512, 2048, true, __bf16>
      <<<dim3(16, 4, 32), 256, 0, stream>>>(xbf, w1t, b1, hbuf, chosen);
  // out = h @ W2[e] + b2[e]      : M=512,K=2048,N=512, f32 out
  gemm_bt_kernel<2048, 512, false, float>
      <<<dim3(4, 4, 32), 256, 0, stream>>>(hbuf, w2t, b2, final_out, chosen);
}